// Round 6
// baseline (1720.517 us; speedup 1.0000x reference)
//
#include <hip/hip_runtime.h>
#include <hip/hip_bf16.h>

// ---------------------------------------------------------------------------
// Problem constants
// ---------------------------------------------------------------------------
#define BB   8
#define CIN  256
#define CHN  256
#define HH   128
#define WWD  128
#define HW   (HH * WWD)        // 16384
#define GRP_ELEMS ((size_t)32 * HW)   // 524288

// borderline-label flag thresholds (mainline logit err sigma ~ 2-4e-6; these are >=500 sigma)
#define FLAG_DL   0.002f
#define FLAG_GAP  5e-4f

// ws BYTE layout. First MEMSET_BYTES are zeroed each call.
#define BO_DSUM1   0        // double[128] (sum[64], sumsq[64]) head1
#define BO_DSUM2   1024     // double[128] head2
#define BO_FSTAT1  2048     // float[128] (mu[64], rstd[64])
#define BO_FSTAT2  2560
#define BO_DSTAT1  3072     // double[128]
#define BO_DSTAT2  4096
#define BO_MEAN    5120     // float[32]
#define BO_CNT     5248     // float[8]
#define BO_TOPK    5280     // float[32]
#define BO_FLAGC   5408     // int (worklist counter)
#define MEMSET_BYTES 8192
#define BO_WL      8192     // int[32768] worklist (not zeroed; counter gates reads)
#define WLCAP      32768

// MFMA-path big buffers (bytes)
#define XP_OFF    139264ull
#define XP_BYTES  134217728ull                 // 8*128*8*128*32 u32
#define HB_OFF    (XP_OFF + XP_BYTES)
#define HB_BYTES  134217728ull                 // 8*256*16384 fp32
#define WH_OFF    (HB_OFF + HB_BYTES)
#define WT_BYTES  1179648ull                   // 9*8*256*32 bf16
#define WL_OFF    (WH_OFF + WT_BYTES)
#define WT32_OFF  (WL_OFF + WT_BYTES)
#define WT32_BYTES 4718592ull                  // 2 heads * 9*256*256 fp32
#define MFMA_NEED (WT32_OFF + WT32_BYTES)

// d_out flat offsets (outputs concatenated in return order, all float)
#define O_DMG   0
#define O_CORN  131072
#define O_PIX   393216
#define O_LAB   917504
#define O_MEAN  1048576
#define O_TOPK  1048608
#define O_AGG   1048640
#define O_ALAB  1048672

typedef __attribute__((ext_vector_type(8))) short short8;
typedef __attribute__((ext_vector_type(4))) float f32x4;

__device__ inline ushort f2bf(float f) {
    uint u = __float_as_uint(f);
    return (ushort)((u + 0x7FFFu + ((u >> 16) & 1u)) >> 16);
}
__device__ inline float bf2f(ushort h) { return __uint_as_float((uint)h << 16); }

__device__ inline void store4v(float* p, float a, float b, float c, float d) {
    *(float4*)p = make_float4(a, b, c, d);
}
__device__ inline void store4v(__hip_bfloat16* p, float a, float b, float c, float d) {
    p[0] = __float2bfloat16(a); p[1] = __float2bfloat16(b);
    p[2] = __float2bfloat16(c); p[3] = __float2bfloat16(d);
}
__device__ inline float ldv(const float* p) { return *p; }
__device__ inline float ldv(const __hip_bfloat16* p) { return __bfloat162float(*p); }

// ===========================================================================
// MFMA PATH
// ===========================================================================

// Pack x [b][ci][y][x] fp32 -> Xp [b][y][cc][x][ci32] u32 (a1<<16 | a0).
__global__ __launch_bounds__(256) void split_pack_x(
    const float* __restrict__ x, uint* __restrict__ Xp)
{
    int bid = blockIdx.x;
    int cc = bid & 7;
    int y  = (bid >> 3) & 127;
    int b  = bid >> 10;
    __shared__ uint tile[32][132];
    for (int i = threadIdx.x; i < 4096; i += 256) {
        int ci = i >> 7, xx = i & 127;
        float v = x[(((size_t)b * 256 + cc * 32 + ci) * 128 + y) * 128 + xx];
        ushort h = f2bf(v);
        ushort l = f2bf(v - bf2f(h));
        tile[ci][xx] = ((uint)l << 16) | (uint)h;
    }
    __syncthreads();
    uint* dst = Xp + ((((size_t)b * 128 + y) * 8 + cc) << 12);
    for (int i = threadIdx.x; i < 4096; i += 256) {
        int xx = i >> 5, ci = i & 31;
        dst[i] = tile[ci][xx];
    }
}

// w [co][ci][3][3] fp32 -> Wth/Wtl SWIZZLED into MFMA B-fragment-linear order:
//   [tap][cc][co-block (co>>4)][lane = (co&15) + 16*(ci5>>3)][j = ci5&7]
// so conv B staging is a lane-linear copy and B-frag ds_read_b128 is the
// stride-1 (conflict-free) pattern. Also Wt32 [tap][ci][co] fp32 for fixup.
__global__ __launch_bounds__(256) void transpose_w(
    const float* __restrict__ w, ushort* __restrict__ Wth,
    ushort* __restrict__ Wtl, float* __restrict__ Wt32)
{
    int idx = blockIdx.x * 256 + threadIdx.x;   // < 589824
    int tap = idx >> 16;
    int rem = idx & 65535;
    int cc  = rem >> 13;
    int co  = (rem >> 5) & 255;
    int ci5 = rem & 31;
    int ci  = cc * 32 + ci5;
    float v = w[((size_t)co * 256 + ci) * 9 + tap];
    ushort h = f2bf(v);
    int sidx = (((tap * 8 + cc) * 16 + (co >> 4)) << 9)
             + (((co & 15) + ((ci5 >> 3) << 4)) << 3) + (ci5 & 7);
    Wth[sidx] = h;
    Wtl[sidx] = f2bf(v - bf2f(h));
    Wt32[((size_t)tap * 256 + ci) * 256 + co] = v;
}

union U8 { uint u[4]; short8 s; };

__device__ inline void unpackA(const uint* p, short8& hi, short8& lo) {
    uint4 r0 = *(const uint4*)p;
    uint4 r1 = *(const uint4*)(p + 4);
    U8 h, l;
    h.u[0] = __builtin_amdgcn_perm(r0.y, r0.x, 0x05040100u);
    h.u[1] = __builtin_amdgcn_perm(r0.w, r0.z, 0x05040100u);
    h.u[2] = __builtin_amdgcn_perm(r1.y, r1.x, 0x05040100u);
    h.u[3] = __builtin_amdgcn_perm(r1.w, r1.z, 0x05040100u);
    l.u[0] = __builtin_amdgcn_perm(r0.y, r0.x, 0x07060302u);
    l.u[1] = __builtin_amdgcn_perm(r0.w, r0.z, 0x07060302u);
    l.u[2] = __builtin_amdgcn_perm(r1.y, r1.x, 0x07060302u);
    l.u[3] = __builtin_amdgcn_perm(r1.w, r1.z, 0x07060302u);
    hi = h.s; lo = l.s;
}

// Conv3x3 via 16x16x32 bf16 MFMA, split-2 (hh + hl + lh). grid (1024, 2).
// B LDS is fragment-linear: [h/l][kx][co-block][lane*8ci] ushort.
#define ALD 36
__global__ __launch_bounds__(256, 2) void conv3x3_mfma(
    const uint* __restrict__ Xp, const ushort* __restrict__ Wth,
    const ushort* __restrict__ Wtl, float* __restrict__ hout,
    double* __restrict__ sums)
{
    __shared__ uint a_lds[130 * ALD];
    __shared__ ushort b_lds[2][3][4096];   // [h/l][kx][8 co-blocks * 512]
    __shared__ float sred[8];

    const int bx  = blockIdx.x;
    const int y   = bx & 127;
    const int b   = bx >> 7;
    const int co0 = blockIdx.y << 7;
    const int tid  = threadIdx.x;
    const int lane = tid & 63;
    const int wv   = tid >> 6;
    const int m = lane & 15;
    const int q = lane >> 4;
    const int wpx = (wv & 1) << 6;
    const int wco = (wv >> 1) << 6;

    if (tid < 8) sred[tid] = 0.f;

    f32x4 acc[4][4];
#pragma unroll
    for (int f = 0; f < 4; f++)
#pragma unroll
        for (int g = 0; g < 4; g++) acc[f][g] = (f32x4){0.f, 0.f, 0.f, 0.f};

    for (int ky = 0; ky < 3; ky++) {
        const int row = y + ky - 1;
        const bool rv = (unsigned)row < 128u;
        const uint* xrow = Xp + (((size_t)(b * 128 + (rv ? row : 0)) * 8) << 12);
        for (int cc = 0; cc < 8; cc++) {
            __syncthreads();
            {
                const uint* s = xrow + ((size_t)cc << 12);
                for (int i = tid; i < 1040; i += 256) {
                    int xi = i >> 3, p4 = i & 7;
                    int xg = xi - 1;
                    uint4 v = make_uint4(0u, 0u, 0u, 0u);
                    if (rv && (unsigned)xg < 128u)
                        v = *(const uint4*)(s + xg * 32 + p4 * 4);
                    *(uint4*)&a_lds[xi * ALD + p4 * 4] = v;
                }
            }
            // B staging: lane-linear copy of swizzled fragments (512 uint4 per h/l)
#pragma unroll
            for (int kx = 0; kx < 3; kx++) {
                int tap = ky * 3 + kx;
                size_t sbase = ((size_t)(tap * 8 + cc) * 16 + (co0 >> 4)) << 9;
                const uint4* sh = (const uint4*)(Wth + sbase);
                const uint4* sl = (const uint4*)(Wtl + sbase);
                uint4* dh  = (uint4*)&b_lds[0][kx][0];
                uint4* dl_ = (uint4*)&b_lds[1][kx][0];
                for (int i = tid; i < 512; i += 256) {
                    dh[i] = sh[i];
                    dl_[i] = sl[i];
                }
            }
            __syncthreads();
#pragma unroll
            for (int kx = 0; kx < 3; kx++) {
                short8 ah[4], al[4], bh[4], bl[4];
#pragma unroll
                for (int f = 0; f < 4; f++) {
                    const uint* p = &a_lds[(wpx + f * 16 + kx + m) * ALD + q * 8];
                    unpackA(p, ah[f], al[f]);
                }
#pragma unroll
                for (int g = 0; g < 4; g++) {
                    int off = (((wco >> 4) + g) << 9) + (lane << 3);
                    bh[g] = *(const short8*)&b_lds[0][kx][off];
                    bl[g] = *(const short8*)&b_lds[1][kx][off];
                }
#pragma unroll
                for (int f = 0; f < 4; f++)
#pragma unroll
                    for (int g = 0; g < 4; g++)
                        acc[f][g] = __builtin_amdgcn_mfma_f32_16x16x32_bf16(ah[f], bh[g], acc[f][g], 0, 0, 0);
#pragma unroll
                for (int f = 0; f < 4; f++)
#pragma unroll
                    for (int g = 0; g < 4; g++)
                        acc[f][g] = __builtin_amdgcn_mfma_f32_16x16x32_bf16(ah[f], bl[g], acc[f][g], 0, 0, 0);
#pragma unroll
                for (int f = 0; f < 4; f++)
#pragma unroll
                    for (int g = 0; g < 4; g++)
                        acc[f][g] = __builtin_amdgcn_mfma_f32_16x16x32_bf16(al[f], bh[g], acc[f][g], 0, 0, 0);
            }
        }
    }

    float s0 = 0.f, q0 = 0.f, s1 = 0.f, q1 = 0.f;
#pragma unroll
    for (int f = 0; f < 4; f++) {
#pragma unroll
        for (int g = 0; g < 4; g++) {
            f32x4 v = acc[f][g];
            float a = v.x + v.y + v.z + v.w;
            float qq = v.x * v.x + v.y * v.y + v.z * v.z + v.w * v.w;
            if (g < 2) { s0 += a; q0 += qq; } else { s1 += a; q1 += qq; }
            int px = wpx + f * 16 + q * 4;
            int co = co0 + wco + g * 16 + m;
            *(f32x4*)&hout[((size_t)(b * 256 + co) * 128 + y) * 128 + px] = v;
        }
    }
    int gl = wco >> 5;
    atomicAdd(&sred[gl],     s0);
    atomicAdd(&sred[gl + 1], s1);
    atomicAdd(&sred[4 + gl],     q0);
    atomicAdd(&sred[4 + gl + 1], q1);
    __syncthreads();
    if (tid < 4) atomicAdd(&sums[b * 8 + (co0 >> 5) + tid], (double)sred[tid]);
    else if (tid < 8) atomicAdd(&sums[64 + b * 8 + (co0 >> 5) + tid - 4], (double)sred[tid]);
}

// ===========================================================================
// fp32 fallback conv (kept for safety; not expected to run)
// ===========================================================================
template <typename HT>
__global__ __launch_bounds__(256) void conv3x3_gn_stats(
    const float* __restrict__ x, const float* __restrict__ w,
    HT* __restrict__ hout, double* __restrict__ sums)
{
    __shared__ float in_lds[8][3][132];
    __shared__ float w_lds[8][9][68];
    __shared__ float sred[2], qred[2];

    const int bx  = blockIdx.x;
    const int y   = bx & (HH - 1);
    const int b   = bx >> 7;
    const int co0 = blockIdx.y << 6;
    const int tid = threadIdx.x;
    if (tid < 2) { sred[tid] = 0.f; qred[tid] = 0.f; }
    const int tco = (tid & 15) << 2;
    const int tox = (tid >> 4) << 3;

    float acc[4][8];
#pragma unroll
    for (int i = 0; i < 4; i++)
#pragma unroll
        for (int j = 0; j < 8; j++) acc[i][j] = 0.f;

    const float* xb = x + (size_t)b * CIN * HW;
    for (int c0 = 0; c0 < CIN; c0 += 8) {
        __syncthreads();
        for (int i = tid; i < 8 * 3 * 130; i += 256) {
            int ci  = i / 390;
            int rem = i - ci * 390;
            int r   = rem / 130;
            int cx  = rem - r * 130;
            int gy  = y + r - 1;
            int gx  = cx - 1;
            float v = 0.f;
            if ((unsigned)gy < HH && (unsigned)gx < WWD)
                v = xb[(size_t)(c0 + ci) * HW + gy * WWD + gx];
            in_lds[ci][r][cx] = v;
        }
        for (int i = tid; i < 64 * 72; i += 256) {
            int co = i / 72;
            int kk = i - co * 72;
            int ci = kk / 9;
            int k9 = kk - ci * 9;
            w_lds[ci][k9][co] = w[((size_t)(co0 + co) * CIN + (c0 + ci)) * 9 + k9];
        }
        __syncthreads();
#pragma unroll
        for (int ci = 0; ci < 8; ci++) {
#pragma unroll
            for (int ky = 0; ky < 3; ky++) {
                const float* rowp = &in_lds[ci][ky][tox];
                float4 a0 = *(const float4*)rowp;
                float4 a1 = *(const float4*)(rowp + 4);
                float2 a2 = *(const float2*)(rowp + 8);
                float in10[10] = {a0.x, a0.y, a0.z, a0.w,
                                  a1.x, a1.y, a1.z, a1.w, a2.x, a2.y};
#pragma unroll
                for (int kx = 0; kx < 3; kx++) {
                    float4 wv = *(const float4*)&w_lds[ci][ky * 3 + kx][tco];
#pragma unroll
                    for (int ox = 0; ox < 8; ox++) {
                        float iv = in10[ox + kx];
                        acc[0][ox] = fmaf(iv, wv.x, acc[0][ox]);
                        acc[1][ox] = fmaf(iv, wv.y, acc[1][ox]);
                        acc[2][ox] = fmaf(iv, wv.z, acc[2][ox]);
                        acc[3][ox] = fmaf(iv, wv.w, acc[3][ox]);
                    }
                }
            }
        }
    }

    float s = 0.f, qv = 0.f;
#pragma unroll
    for (int oc = 0; oc < 4; oc++)
#pragma unroll
        for (int ox = 0; ox < 8; ox++) { float v = acc[oc][ox]; s += v; qv = fmaf(v, v, qv); }
#pragma unroll
    for (int oc = 0; oc < 4; oc++) {
        size_t base = ((size_t)(b * CHN + co0 + tco + oc)) * HW + y * WWD + tox;
        store4v(hout + base,     acc[oc][0], acc[oc][1], acc[oc][2], acc[oc][3]);
        store4v(hout + base + 4, acc[oc][4], acc[oc][5], acc[oc][6], acc[oc][7]);
    }
    const int gsel = tco >> 5;
    atomicAdd(&sred[gsel], s);
    atomicAdd(&qred[gsel], qv);
    __syncthreads();
    if (tid < 2) {
        int grp = (co0 >> 5) + tid;
        atomicAdd(&sums[b * 8 + grp],      (double)sred[tid]);
        atomicAdd(&sums[64 + b * 8 + grp], (double)qred[tid]);
    }
}

// ===========================================================================
// GN finalize: double sums -> float stats (mainline) + double stats (fixup)
// ===========================================================================
__global__ void gn_finalize(const double* __restrict__ dsums,
                            float* __restrict__ fstats, double* __restrict__ dstats)
{
    int i = threadIdx.x;
    if (i < 64) {
        double inv = 1.0 / (double)GRP_ELEMS;
        double mu  = dsums[i] * inv;
        double ex2 = dsums[64 + i] * inv;
        double var = ex2 - mu * mu;
        double rs  = 1.0 / sqrt(var + 1e-5);
        fstats[i]      = (float)mu;
        fstats[64 + i] = (float)rs;
        dstats[i]      = mu;
        dstats[64 + i] = rs;
    }
}

// ---------------------------------------------------------------------------
// GN affine -> exact GELU -> 1x1 conv (+bias). grid (64, B).
// ---------------------------------------------------------------------------
template <typename HT>
__global__ __launch_bounds__(256) void gn_head(
    const HT* __restrict__ hbuf,
    const float* __restrict__ gs, const float* __restrict__ gb,
    const float* __restrict__ w2, const float* __restrict__ b2,
    const float* __restrict__ stats,
    float* __restrict__ out, int nout)
{
    __shared__ float sc[256], sh[256], w2s[2][256];
    const int b = blockIdx.y;
    const int p = blockIdx.x * 256 + threadIdx.x;
    {
        int c = threadIdx.x;
        float mu = stats[b * 8 + (c >> 5)];
        float rs = stats[64 + b * 8 + (c >> 5)];
        float s  = gs[c] * rs;
        sc[c] = s;
        sh[c] = gb[c] - mu * s;
        w2s[0][c] = w2[c];
        w2s[1][c] = (nout > 1) ? w2[256 + c] : 0.f;
    }
    __syncthreads();
    const HT* hp = hbuf + (size_t)b * CHN * HW + p;
    float a0 = 0.f, a1 = 0.f;
    for (int c = 0; c < 256; c++) {
        float v = ldv(hp + (size_t)c * HW);
        v = fmaf(v, sc[c], sh[c]);
        float g = 0.5f * v * (1.f + erff(v * 0.70710678118654752440f));
        a0 = fmaf(g, w2s[0][c], a0);
        a1 = fmaf(g, w2s[1][c], a1);
    }
    out[(size_t)b * nout * HW + p] = a0 + b2[0];
    if (nout > 1) out[(size_t)b * nout * HW + HW + p] = a1 + b2[1];
}

// ---------------------------------------------------------------------------
// Decode + masked-mean accumulation + borderline flagging.
// ---------------------------------------------------------------------------
__global__ __launch_bounds__(256) void decode_kernel(
    float* __restrict__ outw, const float* __restrict__ mask,
    float* __restrict__ meanacc, float* __restrict__ cntacc,
    int* __restrict__ flagcnt, int* __restrict__ wl)
{
    const int b = blockIdx.y;
    const int p = blockIdx.x * 256 + threadIdx.x;

    float dl = outw[O_DMG + b * HW + p];
    float c0 = outw[O_CORN + (b * 2 + 0) * HW + p];
    float c1 = outw[O_CORN + (b * 2 + 1) * HW + p];

    float s0 = 1.f / (1.f + expf(-c0));
    float s1 = 1.f / (1.f + expf(-c1));
    float t0 = s0, t1 = s0 * s1;
    float e0 = fmaxf(1.f - t0, 1e-8f);
    float e1 = fmaxf(t0 - t1, 1e-8f);
    float e2 = fmaxf(t1, 1e-8f);
    float es = fmaxf(e0 + e1 + e2, 1e-8f);
    e0 /= es; e1 /= es; e2 /= es;

    float pd = 1.f / (1.f + expf(-dl));
    float q0 = fmaxf(1.f - pd, 1e-8f);
    float q1 = fmaxf(pd * e0, 1e-8f);
    float q2 = fmaxf(pd * e1, 1e-8f);
    float q3 = fmaxf(pd * e2, 1e-8f);
    float qs = fmaxf(q0 + q1 + q2 + q3, 1e-8f);
    q0 /= qs; q1 /= qs; q2 /= qs; q3 /= qs;

    outw[O_PIX + ((size_t)b * 4 + 0) * HW + p] = q0;
    outw[O_PIX + ((size_t)b * 4 + 1) * HW + p] = q1;
    outw[O_PIX + ((size_t)b * 4 + 2) * HW + p] = q2;
    outw[O_PIX + ((size_t)b * 4 + 3) * HW + p] = q3;

    int am = 0; float bv = e0;
    if (e1 > bv) { bv = e1; am = 1; }
    if (e2 > bv) { bv = e2; am = 2; }
    outw[O_LAB + b * HW + p] = (pd >= 0.5f) ? (float)(am + 1) : 0.f;

    // flag borderline label decisions for fp64 fixup (>=500 sigma margins)
    bool flag = (fabsf(dl) < FLAG_DL);
    {
        float top1 = e0, top2 = fmaxf(e1, e2);
        if (e1 > top1) { top1 = e1; top2 = fmaxf(e0, e2); }
        if (e2 > top1) { top1 = e2; top2 = fmaxf(e0, e1); }
        if ((top1 - top2 < FLAG_GAP) && (dl > -FLAG_DL)) flag = true;
    }
    if (flag) {
        int idx = atomicAdd(flagcnt, 1);
        if (idx < WLCAP) wl[idx] = b * HW + p;
    }

    bool valid = mask[b * HW + p] > 0.5f;
    float vm = valid ? 1.f : 0.f;
    float v0 = valid ? q0 : 0.f, v1 = valid ? q1 : 0.f;
    float v2 = valid ? q2 : 0.f, v3 = valid ? q3 : 0.f;

#pragma unroll
    for (int o = 32; o; o >>= 1) {
        v0 += __shfl_down(v0, o); v1 += __shfl_down(v1, o);
        v2 += __shfl_down(v2, o); v3 += __shfl_down(v3, o);
        vm += __shfl_down(vm, o);
    }
    __shared__ float racc[5];
    if (threadIdx.x < 5) racc[threadIdx.x] = 0.f;
    __syncthreads();
    if ((threadIdx.x & 63) == 0) {
        atomicAdd(&racc[0], v0); atomicAdd(&racc[1], v1);
        atomicAdd(&racc[2], v2); atomicAdd(&racc[3], v3);
        atomicAdd(&racc[4], vm);
    }
    __syncthreads();
    if (threadIdx.x < 4) atomicAdd(&meanacc[b * 4 + threadIdx.x], racc[threadIdx.x]);
    if (threadIdx.x == 4) atomicAdd(&cntacc[b], racc[4]);
}

// ---------------------------------------------------------------------------
// fp64 fixup of pred_labels at flagged pixels. ONE pixel per block iteration.
// 4 waves split the j=2304 reduction (576 each); lane owns 4 couts (float4
// weight loads); j chunked 8-deep so 8 loads are in flight (latency-tolerant).
// grid 512, block 256.
// ---------------------------------------------------------------------------
__global__ __launch_bounds__(256) void fixup_labels(
    const float* __restrict__ x, const float* __restrict__ Wt32,
    const float* __restrict__ dgs, const float* __restrict__ dgb,
    const float* __restrict__ dw2, const float* __restrict__ db2,
    const float* __restrict__ sgs, const float* __restrict__ sgb,
    const float* __restrict__ sw2, const float* __restrict__ sb2,
    const double* __restrict__ dstat1, const double* __restrict__ dstat2,
    const int* __restrict__ wl, const int* __restrict__ wcnt,
    float* __restrict__ out)
{
    __shared__ float xp[2304];          // [tap*256+ci] patch for this pixel
    __shared__ double dpart[4][256];    // per-wave partial h[c]
    __shared__ double wred[3][4];       // [logit][wave]

    int count = *wcnt;
    if (count > WLCAP) count = WLCAP;
    const int tid  = threadIdx.x;
    const int lane = tid & 63;
    const int wv   = tid >> 6;
    const int c4   = lane << 2;         // this lane's first cout
    const int j0   = wv * 576;

    for (int pix = blockIdx.x; pix < count; pix += gridDim.x) {
        __syncthreads();   // protect xp/dpart reuse across iterations
        const int pid = wl[pix];
        const int b = pid >> 14, yy = (pid >> 7) & 127, xx = pid & 127;
        // stage the 3x3x256 input patch (coalesced: consecutive tid -> consecutive ci)
        for (int i = tid; i < 2304; i += 256) {
            int t = i >> 8, ci = i & 255;
            int ky = t / 3, kx = t - ky * 3;
            int gy = yy + ky - 1, gx = xx + kx - 1;
            float v = 0.f;
            if ((unsigned)gy < 128u && (unsigned)gx < 128u)
                v = x[(((size_t)b * 256 + ci) * 128 + gy) * 128 + gx];
            xp[i] = v;
        }
        __syncthreads();

        for (int head = 0; head < 2; head++) {
            const float* gs  = head ? sgs : dgs;
            const float* gb  = head ? sgb : dgb;
            const float* w2  = head ? sw2 : dw2;
            const double* st = head ? dstat2 : dstat1;
            const float* wt  = Wt32 + (size_t)head * 589824;

            // ---- wave-sliced GEMV: h[c4..c4+3] partial over j in [j0, j0+576) ----
            double a0 = 0.0, a1 = 0.0, a2 = 0.0, a3 = 0.0;
            for (int jc = 0; jc < 576; jc += 8) {
                float4 wv4[8];
#pragma unroll
                for (int u = 0; u < 8; u++)
                    wv4[u] = *(const float4*)&wt[(size_t)(j0 + jc + u) * 256 + c4];
#pragma unroll
                for (int u = 0; u < 8; u++) {
                    double xv = (double)xp[j0 + jc + u];
                    a0 += xv * (double)wv4[u].x;
                    a1 += xv * (double)wv4[u].y;
                    a2 += xv * (double)wv4[u].z;
                    a3 += xv * (double)wv4[u].w;
                }
            }
            dpart[wv][c4]     = a0;
            dpart[wv][c4 + 1] = a1;
            dpart[wv][c4 + 2] = a2;
            dpart[wv][c4 + 3] = a3;
            __syncthreads();

            // ---- per-c: combine waves, GN -> GELU -> w2 dot, block reduce ----
            {
                const int c = tid;
                double h = dpart[0][c] + dpart[1][c] + dpart[2][c] + dpart[3][c];
                double mu = st[b * 8 + (c >> 5)];
                double rs = st[64 + b * 8 + (c >> 5)];
                double v = (h - mu) * rs * (double)gs[c] + (double)gb[c];
                double g = 0.5 * v * (1.0 + erf(v * 0.70710678118654752440));
                double r0 = g * (double)w2[c];
#pragma unroll
                for (int o = 32; o; o >>= 1) r0 += __shfl_down(r0, o);
                if (lane == 0) wred[head][wv] = r0;
                if (head == 1) {
                    double r1 = g * (double)w2[256 + c];
#pragma unroll
                    for (int o = 32; o; o >>= 1) r1 += __shfl_down(r1, o);
                    if (lane == 0) wred[2][wv] = r1;
                }
            }
            __syncthreads();   // before next head overwrites dpart
        }

        if (tid == 0) {
            double dlv = wred[0][0] + wred[0][1] + wred[0][2] + wred[0][3] + (double)db2[0];
            double c0v = wred[1][0] + wred[1][1] + wred[1][2] + wred[1][3] + (double)sb2[0];
            double c1v = wred[2][0] + wred[2][1] + wred[2][2] + wred[2][3] + (double)sb2[1];
            double s0 = 1.0 / (1.0 + exp(-c0v));
            double s1 = 1.0 / (1.0 + exp(-c1v));
            double t0 = s0, t1 = s0 * s1;
            double e0 = fmax(1.0 - t0, 1e-8);
            double e1 = fmax(t0 - t1, 1e-8);
            double e2 = fmax(t1, 1e-8);
            int am = 0; double bv = e0;
            if (e1 > bv) { bv = e1; am = 1; }
            if (e2 > bv) { bv = e2; am = 2; }
            out[O_LAB + pid] = (dlv >= 0.0) ? (float)(am + 1) : 0.f;
        }
    }
}

// ---------------------------------------------------------------------------
// Exact masked top-k mean per (b,c) via radix select. 32 blocks.
// ---------------------------------------------------------------------------
__global__ __launch_bounds__(256) void topk_kernel(
    const float* __restrict__ outw, const float* __restrict__ mask,
    const float* __restrict__ cntacc, float* __restrict__ topkout)
{
    const int b = blockIdx.x >> 2;
    const int c = blockIdx.x & 3;
    const int tid = threadIdx.x;

    __shared__ int hist[256];
    __shared__ unsigned s_prefix;
    __shared__ int s_want;
    __shared__ float s_red[4];
    __shared__ int s_redi[4];

    float cntf = cntacc[b];
    int cnt = (int)cntf;
    int k = (int)rintf(cntf * 0.2f);
    if (k < 1) k = 1;
    int kmax = cnt > 1 ? cnt : 1;
    if (k > kmax) k = kmax;

    if (tid == 0) { s_prefix = 0u; s_want = k; }

    const float* pv = outw + O_PIX + ((size_t)b * 4 + c) * HW;
    const float* pm = mask + (size_t)b * HW;

    for (int pass = 0; pass < 4; pass++) {
        hist[tid] = 0;
        __syncthreads();
        const int shift = 24 - 8 * pass;
        const unsigned pmask = pass ? (0xFFFFFFFFu << (shift + 8)) : 0u;
        const unsigned prefix = s_prefix;
        for (int p = tid; p < HW; p += 256) {
            float v = (pm[p] > 0.5f) ? pv[p] : -1.0f;
            unsigned bits = __float_as_uint(v);
            unsigned u = (bits & 0x80000000u) ? ~bits : (bits | 0x80000000u);
            if ((u & pmask) == prefix) atomicAdd(&hist[(u >> shift) & 255], 1);
        }
        __syncthreads();
        if (tid == 0) {
            int want = s_want;
            int bin = 255;
            while (bin > 0) {
                int h = hist[bin];
                if (want <= h) break;
                want -= h;
                bin--;
            }
            s_want = want;
            s_prefix = prefix | ((unsigned)bin << shift);
        }
        __syncthreads();
    }
    const unsigned tau = s_prefix;

    float sgt = 0.f; int cgt = 0;
    for (int p = tid; p < HW; p += 256) {
        float v = (pm[p] > 0.5f) ? pv[p] : -1.0f;
        unsigned bits = __float_as_uint(v);
        unsigned u = (bits & 0x80000000u) ? ~bits : (bits | 0x80000000u);
        if (u > tau) { sgt += v; cgt++; }
    }
#pragma unroll
    for (int o = 32; o; o >>= 1) { sgt += __shfl_down(sgt, o); cgt += __shfl_down(cgt, o); }
    if ((tid & 63) == 0) { s_red[tid >> 6] = sgt; s_redi[tid >> 6] = cgt; }
    __syncthreads();
    if (tid == 0) {
        float S = s_red[0] + s_red[1] + s_red[2] + s_red[3];
        int   C = s_redi[0] + s_redi[1] + s_redi[2] + s_redi[3];
        unsigned tb = (tau & 0x80000000u) ? (tau & 0x7FFFFFFFu) : ~tau;
        float tf = __uint_as_float(tb);
        float total = S + (float)(k - C) * tf;
        topkout[b * 4 + c] = total / (float)k;
    }
}

__device__ inline void norm4(float* p)
{
    float a = fmaxf(p[0], 1e-8f), b = fmaxf(p[1], 1e-8f);
    float c = fmaxf(p[2], 1e-8f), d = fmaxf(p[3], 1e-8f);
    float s = fmaxf(a + b + c + d, 1e-8f);
    p[0] = a / s; p[1] = b / s; p[2] = c / s; p[3] = d / s;
}

__global__ void final_kernel(const float* __restrict__ meanacc,
                             const float* __restrict__ cntacc,
                             const float* __restrict__ topkv,
                             float* __restrict__ outw)
{
    int b = threadIdx.x;
    if (b >= 8) return;
    float cnt = cntacc[b];
    bool zero = (cnt == 0.f);
    float denom = fmaxf(cnt, 1.f);
    float m[4], t[4], a[4];
#pragma unroll
    for (int c = 0; c < 4; c++) {
        m[c] = zero ? 0.25f : meanacc[b * 4 + c] / denom;
        t[c] = zero ? 0.25f : topkv[b * 4 + c];
    }
    norm4(m); norm4(t);
#pragma unroll
    for (int c = 0; c < 4; c++) a[c] = 0.7f * m[c] + 0.3f * t[c];
    norm4(a);
    int am = 0; float bv = a[0];
#pragma unroll
    for (int c = 1; c < 4; c++) if (a[c] > bv) { bv = a[c]; am = c; }
#pragma unroll
    for (int c = 0; c < 4; c++) {
        outw[O_MEAN + b * 4 + c] = m[c];
        outw[O_TOPK + b * 4 + c] = t[c];
        outw[O_AGG  + b * 4 + c] = a[c];
    }
    outw[O_ALAB + b] = (float)am;
}

// ---------------------------------------------------------------------------
extern "C" void kernel_launch(void* const* d_in, const int* in_sizes, int n_in,
                              void* d_out, int out_size, void* d_ws, size_t ws_size,
                              hipStream_t stream)
{
    (void)in_sizes; (void)n_in; (void)out_size;
    const float* x    = (const float*)d_in[0];
    const float* mask = (const float*)d_in[1];
    const float* dw1  = (const float*)d_in[2];
    const float* dgs  = (const float*)d_in[3];
    const float* dgb  = (const float*)d_in[4];
    const float* dw2  = (const float*)d_in[5];
    const float* db2  = (const float*)d_in[6];
    const float* sw1  = (const float*)d_in[7];
    const float* sgs  = (const float*)d_in[8];
    const float* sgb  = (const float*)d_in[9];
    const float* sw2  = (const float*)d_in[10];
    const float* sb2  = (const float*)d_in[11];
    float* out = (float*)d_out;

    char* wsb = (char*)d_ws;
    double* dsum1  = (double*)(wsb + BO_DSUM1);
    double* dsum2  = (double*)(wsb + BO_DSUM2);
    float*  fstat1 = (float*)(wsb + BO_FSTAT1);
    float*  fstat2 = (float*)(wsb + BO_FSTAT2);
    double* dstat1 = (double*)(wsb + BO_DSTAT1);
    double* dstat2 = (double*)(wsb + BO_DSTAT2);
    float*  meanacc = (float*)(wsb + BO_MEAN);
    float*  cntacc  = (float*)(wsb + BO_CNT);
    float*  topkv   = (float*)(wsb + BO_TOPK);
    int*    flagc   = (int*)(wsb + BO_FLAGC);
    int*    wl      = (int*)(wsb + BO_WL);

    hipMemsetAsync(d_ws, 0, MEMSET_BYTES, stream);

    dim3 pgrid(64, BB);

    if (ws_size >= MFMA_NEED) {
        uint*   Xp   = (uint*)(wsb + XP_OFF);
        float*  hb   = (float*)(wsb + HB_OFF);
        ushort* Wth  = (ushort*)(wsb + WH_OFF);
        ushort* Wtl  = (ushort*)(wsb + WL_OFF);
        float*  Wt32 = (float*)(wsb + WT32_OFF);

        split_pack_x<<<8192, 256, 0, stream>>>(x, Xp);

        dim3 cgrid(1024, 2);
        transpose_w<<<2304, 256, 0, stream>>>(dw1, Wth, Wtl, Wt32);
        conv3x3_mfma<<<cgrid, 256, 0, stream>>>(Xp, Wth, Wtl, hb, dsum1);
        gn_finalize<<<1, 64, 0, stream>>>(dsum1, fstat1, dstat1);
        gn_head<float><<<pgrid, 256, 0, stream>>>(hb, dgs, dgb, dw2, db2,
                                                  fstat1, out + O_DMG, 1);
        transpose_w<<<2304, 256, 0, stream>>>(sw1, Wth, Wtl, Wt32 + 589824);
        conv3x3_mfma<<<cgrid, 256, 0, stream>>>(Xp, Wth, Wtl, hb, dsum2);
        gn_finalize<<<1, 64, 0, stream>>>(dsum2, fstat2, dstat2);
        gn_head<float><<<pgrid, 256, 0, stream>>>(hb, sgs, sgb, sw2, sb2,
                                                  fstat2, out + O_CORN, 2);

        decode_kernel<<<pgrid, 256, 0, stream>>>(out, mask, meanacc, cntacc, flagc, wl);
        fixup_labels<<<512, 256, 0, stream>>>(x, Wt32, dgs, dgb, dw2, db2,
                                              sgs, sgb, sw2, sb2,
                                              dstat1, dstat2, wl, flagc, out);
        topk_kernel<<<32, 256, 0, stream>>>(out, mask, cntacc, topkv);
        final_kernel<<<1, 64, 0, stream>>>(meanacc, cntacc, topkv, out);
    } else {
        void* hbuf = wsb + XP_OFF;
        dim3 cgrid(HH * BB, CHN / 64);
        const size_t needF32 = XP_OFF + (size_t)BB * CHN * HW * sizeof(float);
        if (ws_size >= needF32) {
            conv3x3_gn_stats<float><<<cgrid, 256, 0, stream>>>(x, dw1, (float*)hbuf, dsum1);
            gn_finalize<<<1, 64, 0, stream>>>(dsum1, fstat1, dstat1);
            gn_head<float><<<pgrid, 256, 0, stream>>>((float*)hbuf, dgs, dgb, dw2, db2,
                                                      fstat1, out + O_DMG, 1);
            conv3x3_gn_stats<float><<<cgrid, 256, 0, stream>>>(x, sw1, (float*)hbuf, dsum2);
            gn_finalize<<<1, 64, 0, stream>>>(dsum2, fstat2, dstat2);
            gn_head<float><<<pgrid, 256, 0, stream>>>((float*)hbuf, sgs, sgb, sw2, sb2,
                                                      fstat2, out + O_CORN, 2);
        } else {
            conv3x3_gn_stats<__hip_bfloat16><<<cgrid, 256, 0, stream>>>(x, dw1, (__hip_bfloat16*)hbuf, dsum1);
            gn_finalize<<<1, 64, 0, stream>>>(dsum1, fstat1, dstat1);
            gn_head<__hip_bfloat16><<<pgrid, 256, 0, stream>>>((__hip_bfloat16*)hbuf, dgs, dgb, dw2, db2,
                                                               fstat1, out + O_DMG, 1);
            conv3x3_gn_stats<__hip_bfloat16><<<cgrid, 256, 0, stream>>>(x, sw1, (__hip_bfloat16*)hbuf, dsum2);
            gn_finalize<<<1, 64, 0, stream>>>(dsum2, fstat2, dstat2);
            gn_head<__hip_bfloat16><<<pgrid, 256, 0, stream>>>((__hip_bfloat16*)hbuf, sgs, sgb, sw2, sb2,
                                                               fstat2, out + O_CORN, 2);
        }
        decode_kernel<<<pgrid, 256, 0, stream>>>(out, mask, meanacc, cntacc, flagc, wl);
        topk_kernel<<<32, 256, 0, stream>>>(out, mask, cntacc, topkv);
        final_kernel<<<1, 64, 0, stream>>>(meanacc, cntacc, topkv, out);
    }
}

// Round 7
// 1515.247 us; speedup vs baseline: 1.1355x; 1.1355x over previous
//
#include <hip/hip_runtime.h>
#include <hip/hip_bf16.h>

// ---------------------------------------------------------------------------
// Problem constants
// ---------------------------------------------------------------------------
#define BB   8
#define CIN  256
#define CHN  256
#define HH   128
#define WWD  128
#define HW   (HH * WWD)        // 16384
#define GRP_ELEMS ((size_t)32 * HW)   // 524288

// borderline-label flag thresholds.
// fp16 2-product logit err sigma <= ~3.5e-4 (incl. possible denorm flush of bl)
// => these are >=10 sigma.
#define FLAG_DL   4e-3f
#define FLAG_GAP  1.5e-3f

// ws BYTE layout. First MEMSET_BYTES are zeroed each call.
#define BO_DSUM1   0        // double[128] (sum[64], sumsq[64]) head1
#define BO_DSUM2   1024     // double[128] head2
#define BO_FSTAT1  2048     // float[128] (mu[64], rstd[64])
#define BO_FSTAT2  2560
#define BO_DSTAT1  3072     // double[128]
#define BO_DSTAT2  4096
#define BO_MEAN    5120     // float[32]
#define BO_CNT     5248     // float[8]
#define BO_TOPK    5280     // float[32]
#define BO_FLAGC   5408     // int (worklist counter)
#define MEMSET_BYTES 8192
#define BO_WL      8192     // int[32768] worklist (not zeroed; counter gates reads)
#define WLCAP      32768

// MFMA-path big buffers (bytes)
#define XP_OFF    139264ull
#define XP_BYTES  67108864ull                  // 8*128*8*128*32 fp16 (ushort)
#define HB_OFF    (XP_OFF + XP_BYTES)
#define HB_BYTES  134217728ull                 // 8*256*16384 fp32
#define WH_OFF    (HB_OFF + HB_BYTES)
#define WT_BYTES  1179648ull                   // 9*8*256*32 fp16
#define WL_OFF    (WH_OFF + WT_BYTES)
#define WT32_OFF  (WL_OFF + WT_BYTES)
#define WT32_BYTES 4718592ull                  // 2 heads * 9*256*256 fp32
#define MFMA_NEED (WT32_OFF + WT32_BYTES)

// d_out flat offsets (outputs concatenated in return order, all float)
#define O_DMG   0
#define O_CORN  131072
#define O_PIX   393216
#define O_LAB   917504
#define O_MEAN  1048576
#define O_TOPK  1048608
#define O_AGG   1048640
#define O_ALAB  1048672

typedef __attribute__((ext_vector_type(8))) _Float16 f16x8;
typedef __attribute__((ext_vector_type(4))) float f32x4;

__device__ inline ushort f2h(float f) {
    _Float16 h = (_Float16)f;
    union { _Float16 h; ushort u; } c; c.h = h; return c.u;
}
__device__ inline float h2f(ushort u) {
    union { ushort u; _Float16 h; } c; c.u = u; return (float)c.h;
}

__device__ inline void store4v(float* p, float a, float b, float c, float d) {
    *(float4*)p = make_float4(a, b, c, d);
}
__device__ inline void store4v(__hip_bfloat16* p, float a, float b, float c, float d) {
    p[0] = __float2bfloat16(a); p[1] = __float2bfloat16(b);
    p[2] = __float2bfloat16(c); p[3] = __float2bfloat16(d);
}
__device__ inline float ldv(const float* p) { return *p; }
__device__ inline float ldv(const __hip_bfloat16* p) { return __bfloat162float(*p); }

// ===========================================================================
// MFMA PATH (fp16, 2-product: h = fp16(x) * (wh + wl))
// ===========================================================================

// Pack x [b][ci][y][x] fp32 -> Xh [b][y][cc][x][ci32] fp16. grid 8192.
__global__ __launch_bounds__(256) void pack_x_f16(
    const float* __restrict__ x, ushort* __restrict__ Xh)
{
    int bid = blockIdx.x;
    int cc = bid & 7;
    int y  = (bid >> 3) & 127;
    int b  = bid >> 10;
    __shared__ ushort tile[32][132];
    for (int i = threadIdx.x; i < 4096; i += 256) {
        int ci = i >> 7, xx = i & 127;
        float v = x[(((size_t)b * 256 + cc * 32 + ci) * 128 + y) * 128 + xx];
        tile[ci][xx] = f2h(v);
    }
    __syncthreads();
    ushort* dst = Xh + ((((size_t)b * 128 + y) * 8 + cc) << 12);
    for (int i = threadIdx.x; i < 4096; i += 256) {
        int xx = i >> 5, ci = i & 31;
        dst[i] = tile[ci][xx];
    }
}

// w [co][ci][3][3] fp32 -> Whh/Whl fp16 hi/lo, SWIZZLED into MFMA B-fragment
// order: [tap][cc][co-block][lane=(co&15)+16*(ci5>>3)][j=ci5&7], so conv B
// staging is lane-linear and B-frag ds_read_b128 is conflict-free.
// Also Wt32 [tap][ci][co] fp32 for the fp64 fixup.
__global__ __launch_bounds__(256) void transpose_w(
    const float* __restrict__ w, ushort* __restrict__ Whh,
    ushort* __restrict__ Whl, float* __restrict__ Wt32)
{
    int idx = blockIdx.x * 256 + threadIdx.x;   // < 589824
    int tap = idx >> 16;
    int rem = idx & 65535;
    int cc  = rem >> 13;
    int co  = (rem >> 5) & 255;
    int ci5 = rem & 31;
    int ci  = cc * 32 + ci5;
    float v = w[((size_t)co * 256 + ci) * 9 + tap];
    ushort h = f2h(v);
    int sidx = (((tap * 8 + cc) * 16 + (co >> 4)) << 9)
             + (((co & 15) + ((ci5 >> 3) << 4)) << 3) + (ci5 & 7);
    Whh[sidx] = h;
    Whl[sidx] = f2h(v - h2f(h));
    Wt32[((size_t)tap * 256 + ci) * 256 + co] = v;
}

// Conv3x3 via 16x16x32 fp16 MFMA, 2 products (a*bh + a*bl). grid (1024, 2).
// A LDS: fp16 [xi 0..129][ci32], row stride 40 ushort (80 B, 16B-aligned,
// 2-way max bank aliasing = free). B LDS fragment-linear.
#define ALD 40
__global__ __launch_bounds__(256, 2) void conv3x3_mfma(
    const ushort* __restrict__ Xh, const ushort* __restrict__ Whh,
    const ushort* __restrict__ Whl, float* __restrict__ hout,
    double* __restrict__ sums)
{
    __shared__ ushort a_lds[130 * ALD];
    __shared__ ushort b_lds[2][3][4096];   // [h/l][kx][8 co-blocks * 512]
    __shared__ float sred[8];

    const int bx  = blockIdx.x;
    const int y   = bx & 127;
    const int b   = bx >> 7;
    const int co0 = blockIdx.y << 7;
    const int tid  = threadIdx.x;
    const int lane = tid & 63;
    const int wv   = tid >> 6;
    const int m = lane & 15;
    const int q = lane >> 4;
    const int wpx = (wv & 1) << 6;
    const int wco = (wv >> 1) << 6;

    if (tid < 8) sred[tid] = 0.f;

    f32x4 acc[4][4];
#pragma unroll
    for (int f = 0; f < 4; f++)
#pragma unroll
        for (int g = 0; g < 4; g++) acc[f][g] = (f32x4){0.f, 0.f, 0.f, 0.f};

    for (int ky = 0; ky < 3; ky++) {
        const int row = y + ky - 1;
        const bool rv = (unsigned)row < 128u;
        const ushort* xrow = Xh + (((size_t)(b * 128 + (rv ? row : 0)) * 8) << 12);
        for (int cc = 0; cc < 8; cc++) {
            __syncthreads();
            // ---- stage A: 130 xi x 32 fp16 (520 uint4) ----
            {
                const ushort* s = xrow + ((size_t)cc << 12);
                for (int i = tid; i < 520; i += 256) {
                    int xi = i >> 2, p4 = i & 3;
                    int xg = xi - 1;
                    uint4 v = make_uint4(0u, 0u, 0u, 0u);
                    if (rv && (unsigned)xg < 128u)
                        v = *(const uint4*)(s + xg * 32 + p4 * 8);
                    *(uint4*)&a_lds[xi * ALD + p4 * 8] = v;
                }
            }
            // ---- stage B: lane-linear copy of swizzled fragments ----
#pragma unroll
            for (int kx = 0; kx < 3; kx++) {
                int tap = ky * 3 + kx;
                size_t sbase = ((size_t)(tap * 8 + cc) * 16 + (co0 >> 4)) << 9;
                const uint4* sh = (const uint4*)(Whh + sbase);
                const uint4* sl = (const uint4*)(Whl + sbase);
                uint4* dh  = (uint4*)&b_lds[0][kx][0];
                uint4* dl_ = (uint4*)&b_lds[1][kx][0];
                for (int i = tid; i < 512; i += 256) {
                    dh[i] = sh[i];
                    dl_[i] = sl[i];
                }
            }
            __syncthreads();
#pragma unroll
            for (int kx = 0; kx < 3; kx++) {
                f16x8 ah[4], bh[4], bl[4];
#pragma unroll
                for (int f = 0; f < 4; f++)
                    ah[f] = *(const f16x8*)&a_lds[(wpx + f * 16 + kx + m) * ALD + q * 8];
#pragma unroll
                for (int g = 0; g < 4; g++) {
                    int off = (((wco >> 4) + g) << 9) + (lane << 3);
                    bh[g] = *(const f16x8*)&b_lds[0][kx][off];
                    bl[g] = *(const f16x8*)&b_lds[1][kx][off];
                }
#pragma unroll
                for (int f = 0; f < 4; f++)
#pragma unroll
                    for (int g = 0; g < 4; g++)
                        acc[f][g] = __builtin_amdgcn_mfma_f32_16x16x32_f16(ah[f], bh[g], acc[f][g], 0, 0, 0);
#pragma unroll
                for (int f = 0; f < 4; f++)
#pragma unroll
                    for (int g = 0; g < 4; g++)
                        acc[f][g] = __builtin_amdgcn_mfma_f32_16x16x32_f16(ah[f], bl[g], acc[f][g], 0, 0, 0);
            }
        }
    }

    float s0 = 0.f, q0 = 0.f, s1 = 0.f, q1 = 0.f;
#pragma unroll
    for (int f = 0; f < 4; f++) {
#pragma unroll
        for (int g = 0; g < 4; g++) {
            f32x4 v = acc[f][g];
            float a = v.x + v.y + v.z + v.w;
            float qq = v.x * v.x + v.y * v.y + v.z * v.z + v.w * v.w;
            if (g < 2) { s0 += a; q0 += qq; } else { s1 += a; q1 += qq; }
            int px = wpx + f * 16 + q * 4;
            int co = co0 + wco + g * 16 + m;
            *(f32x4*)&hout[((size_t)(b * 256 + co) * 128 + y) * 128 + px] = v;
        }
    }
    int gl = wco >> 5;
    atomicAdd(&sred[gl],     s0);
    atomicAdd(&sred[gl + 1], s1);
    atomicAdd(&sred[4 + gl],     q0);
    atomicAdd(&sred[4 + gl + 1], q1);
    __syncthreads();
    if (tid < 4) atomicAdd(&sums[b * 8 + (co0 >> 5) + tid], (double)sred[tid]);
    else if (tid < 8) atomicAdd(&sums[64 + b * 8 + (co0 >> 5) + tid - 4], (double)sred[tid]);
}

// ===========================================================================
// fp32 fallback conv (kept for safety; not expected to run)
// ===========================================================================
template <typename HT>
__global__ __launch_bounds__(256) void conv3x3_gn_stats(
    const float* __restrict__ x, const float* __restrict__ w,
    HT* __restrict__ hout, double* __restrict__ sums)
{
    __shared__ float in_lds[8][3][132];
    __shared__ float w_lds[8][9][68];
    __shared__ float sred[2], qred[2];

    const int bx  = blockIdx.x;
    const int y   = bx & (HH - 1);
    const int b   = bx >> 7;
    const int co0 = blockIdx.y << 6;
    const int tid = threadIdx.x;
    if (tid < 2) { sred[tid] = 0.f; qred[tid] = 0.f; }
    const int tco = (tid & 15) << 2;
    const int tox = (tid >> 4) << 3;

    float acc[4][8];
#pragma unroll
    for (int i = 0; i < 4; i++)
#pragma unroll
        for (int j = 0; j < 8; j++) acc[i][j] = 0.f;

    const float* xb = x + (size_t)b * CIN * HW;
    for (int c0 = 0; c0 < CIN; c0 += 8) {
        __syncthreads();
        for (int i = tid; i < 8 * 3 * 130; i += 256) {
            int ci  = i / 390;
            int rem = i - ci * 390;
            int r   = rem / 130;
            int cx  = rem - r * 130;
            int gy  = y + r - 1;
            int gx  = cx - 1;
            float v = 0.f;
            if ((unsigned)gy < HH && (unsigned)gx < WWD)
                v = xb[(size_t)(c0 + ci) * HW + gy * WWD + gx];
            in_lds[ci][r][cx] = v;
        }
        for (int i = tid; i < 64 * 72; i += 256) {
            int co = i / 72;
            int kk = i - co * 72;
            int ci = kk / 9;
            int k9 = kk - ci * 9;
            w_lds[ci][k9][co] = w[((size_t)(co0 + co) * CIN + (c0 + ci)) * 9 + k9];
        }
        __syncthreads();
#pragma unroll
        for (int ci = 0; ci < 8; ci++) {
#pragma unroll
            for (int ky = 0; ky < 3; ky++) {
                const float* rowp = &in_lds[ci][ky][tox];
                float4 a0 = *(const float4*)rowp;
                float4 a1 = *(const float4*)(rowp + 4);
                float2 a2 = *(const float2*)(rowp + 8);
                float in10[10] = {a0.x, a0.y, a0.z, a0.w,
                                  a1.x, a1.y, a1.z, a1.w, a2.x, a2.y};
#pragma unroll
                for (int kx = 0; kx < 3; kx++) {
                    float4 wv = *(const float4*)&w_lds[ci][ky * 3 + kx][tco];
#pragma unroll
                    for (int ox = 0; ox < 8; ox++) {
                        float iv = in10[ox + kx];
                        acc[0][ox] = fmaf(iv, wv.x, acc[0][ox]);
                        acc[1][ox] = fmaf(iv, wv.y, acc[1][ox]);
                        acc[2][ox] = fmaf(iv, wv.z, acc[2][ox]);
                        acc[3][ox] = fmaf(iv, wv.w, acc[3][ox]);
                    }
                }
            }
        }
    }

    float s = 0.f, qv = 0.f;
#pragma unroll
    for (int oc = 0; oc < 4; oc++)
#pragma unroll
        for (int ox = 0; ox < 8; ox++) { float v = acc[oc][ox]; s += v; qv = fmaf(v, v, qv); }
#pragma unroll
    for (int oc = 0; oc < 4; oc++) {
        size_t base = ((size_t)(b * CHN + co0 + tco + oc)) * HW + y * WWD + tox;
        store4v(hout + base,     acc[oc][0], acc[oc][1], acc[oc][2], acc[oc][3]);
        store4v(hout + base + 4, acc[oc][4], acc[oc][5], acc[oc][6], acc[oc][7]);
    }
    const int gsel = tco >> 5;
    atomicAdd(&sred[gsel], s);
    atomicAdd(&qred[gsel], qv);
    __syncthreads();
    if (tid < 2) {
        int grp = (co0 >> 5) + tid;
        atomicAdd(&sums[b * 8 + grp],      (double)sred[tid]);
        atomicAdd(&sums[64 + b * 8 + grp], (double)qred[tid]);
    }
}

// ===========================================================================
// GN finalize: double sums -> float stats (mainline) + double stats (fixup)
// ===========================================================================
__global__ void gn_finalize(const double* __restrict__ dsums,
                            float* __restrict__ fstats, double* __restrict__ dstats)
{
    int i = threadIdx.x;
    if (i < 64) {
        double inv = 1.0 / (double)GRP_ELEMS;
        double mu  = dsums[i] * inv;
        double ex2 = dsums[64 + i] * inv;
        double var = ex2 - mu * mu;
        double rs  = 1.0 / sqrt(var + 1e-5);
        fstats[i]      = (float)mu;
        fstats[64 + i] = (float)rs;
        dstats[i]      = mu;
        dstats[64 + i] = rs;
    }
}

// ---------------------------------------------------------------------------
// GN affine -> exact GELU -> 1x1 conv (+bias). grid (64, B).
// ---------------------------------------------------------------------------
template <typename HT>
__global__ __launch_bounds__(256) void gn_head(
    const HT* __restrict__ hbuf,
    const float* __restrict__ gs, const float* __restrict__ gb,
    const float* __restrict__ w2, const float* __restrict__ b2,
    const float* __restrict__ stats,
    float* __restrict__ out, int nout)
{
    __shared__ float sc[256], sh[256], w2s[2][256];
    const int b = blockIdx.y;
    const int p = blockIdx.x * 256 + threadIdx.x;
    {
        int c = threadIdx.x;
        float mu = stats[b * 8 + (c >> 5)];
        float rs = stats[64 + b * 8 + (c >> 5)];
        float s  = gs[c] * rs;
        sc[c] = s;
        sh[c] = gb[c] - mu * s;
        w2s[0][c] = w2[c];
        w2s[1][c] = (nout > 1) ? w2[256 + c] : 0.f;
    }
    __syncthreads();
    const HT* hp = hbuf + (size_t)b * CHN * HW + p;
    float a0 = 0.f, a1 = 0.f;
    for (int c = 0; c < 256; c++) {
        float v = ldv(hp + (size_t)c * HW);
        v = fmaf(v, sc[c], sh[c]);
        float g = 0.5f * v * (1.f + erff(v * 0.70710678118654752440f));
        a0 = fmaf(g, w2s[0][c], a0);
        a1 = fmaf(g, w2s[1][c], a1);
    }
    out[(size_t)b * nout * HW + p] = a0 + b2[0];
    if (nout > 1) out[(size_t)b * nout * HW + HW + p] = a1 + b2[1];
}

// ---------------------------------------------------------------------------
// Decode + masked-mean accumulation + borderline flagging.
// ---------------------------------------------------------------------------
__global__ __launch_bounds__(256) void decode_kernel(
    float* __restrict__ outw, const float* __restrict__ mask,
    float* __restrict__ meanacc, float* __restrict__ cntacc,
    int* __restrict__ flagcnt, int* __restrict__ wl)
{
    const int b = blockIdx.y;
    const int p = blockIdx.x * 256 + threadIdx.x;

    float dl = outw[O_DMG + b * HW + p];
    float c0 = outw[O_CORN + (b * 2 + 0) * HW + p];
    float c1 = outw[O_CORN + (b * 2 + 1) * HW + p];

    float s0 = 1.f / (1.f + expf(-c0));
    float s1 = 1.f / (1.f + expf(-c1));
    float t0 = s0, t1 = s0 * s1;
    float e0 = fmaxf(1.f - t0, 1e-8f);
    float e1 = fmaxf(t0 - t1, 1e-8f);
    float e2 = fmaxf(t1, 1e-8f);
    float es = fmaxf(e0 + e1 + e2, 1e-8f);
    e0 /= es; e1 /= es; e2 /= es;

    float pd = 1.f / (1.f + expf(-dl));
    float q0 = fmaxf(1.f - pd, 1e-8f);
    float q1 = fmaxf(pd * e0, 1e-8f);
    float q2 = fmaxf(pd * e1, 1e-8f);
    float q3 = fmaxf(pd * e2, 1e-8f);
    float qs = fmaxf(q0 + q1 + q2 + q3, 1e-8f);
    q0 /= qs; q1 /= qs; q2 /= qs; q3 /= qs;

    outw[O_PIX + ((size_t)b * 4 + 0) * HW + p] = q0;
    outw[O_PIX + ((size_t)b * 4 + 1) * HW + p] = q1;
    outw[O_PIX + ((size_t)b * 4 + 2) * HW + p] = q2;
    outw[O_PIX + ((size_t)b * 4 + 3) * HW + p] = q3;

    int am = 0; float bv = e0;
    if (e1 > bv) { bv = e1; am = 1; }
    if (e2 > bv) { bv = e2; am = 2; }
    outw[O_LAB + b * HW + p] = (pd >= 0.5f) ? (float)(am + 1) : 0.f;

    // flag borderline label decisions for fp64 fixup (>=10 sigma margins)
    bool flag = (fabsf(dl) < FLAG_DL);
    {
        float top1 = e0, top2 = fmaxf(e1, e2);
        if (e1 > top1) { top1 = e1; top2 = fmaxf(e0, e2); }
        if (e2 > top1) { top1 = e2; top2 = fmaxf(e0, e1); }
        if ((top1 - top2 < FLAG_GAP) && (dl > -FLAG_DL)) flag = true;
    }
    if (flag) {
        int idx = atomicAdd(flagcnt, 1);
        if (idx < WLCAP) wl[idx] = b * HW + p;
    }

    bool valid = mask[b * HW + p] > 0.5f;
    float vm = valid ? 1.f : 0.f;
    float v0 = valid ? q0 : 0.f, v1 = valid ? q1 : 0.f;
    float v2 = valid ? q2 : 0.f, v3 = valid ? q3 : 0.f;

#pragma unroll
    for (int o = 32; o; o >>= 1) {
        v0 += __shfl_down(v0, o); v1 += __shfl_down(v1, o);
        v2 += __shfl_down(v2, o); v3 += __shfl_down(v3, o);
        vm += __shfl_down(vm, o);
    }
    __shared__ float racc[5];
    if (threadIdx.x < 5) racc[threadIdx.x] = 0.f;
    __syncthreads();
    if ((threadIdx.x & 63) == 0) {
        atomicAdd(&racc[0], v0); atomicAdd(&racc[1], v1);
        atomicAdd(&racc[2], v2); atomicAdd(&racc[3], v3);
        atomicAdd(&racc[4], vm);
    }
    __syncthreads();
    if (threadIdx.x < 4) atomicAdd(&meanacc[b * 4 + threadIdx.x], racc[threadIdx.x]);
    if (threadIdx.x == 4) atomicAdd(&cntacc[b], racc[4]);
}

// ---------------------------------------------------------------------------
// fp64 fixup of pred_labels at flagged pixels. ONE pixel per block iteration.
// 4 waves split the j=2304 reduction; lane owns 4 couts (float4 weight
// loads); j chunked 8-deep for latency tolerance. grid 512, block 256.
// ---------------------------------------------------------------------------
__global__ __launch_bounds__(256) void fixup_labels(
    const float* __restrict__ x, const float* __restrict__ Wt32,
    const float* __restrict__ dgs, const float* __restrict__ dgb,
    const float* __restrict__ dw2, const float* __restrict__ db2,
    const float* __restrict__ sgs, const float* __restrict__ sgb,
    const float* __restrict__ sw2, const float* __restrict__ sb2,
    const double* __restrict__ dstat1, const double* __restrict__ dstat2,
    const int* __restrict__ wl, const int* __restrict__ wcnt,
    float* __restrict__ out)
{
    __shared__ float xp[2304];          // [tap*256+ci] patch for this pixel
    __shared__ double dpart[4][256];    // per-wave partial h[c]
    __shared__ double wred[3][4];       // [logit][wave]

    int count = *wcnt;
    if (count > WLCAP) count = WLCAP;
    const int tid  = threadIdx.x;
    const int lane = tid & 63;
    const int wv   = tid >> 6;
    const int c4   = lane << 2;         // this lane's first cout
    const int j0   = wv * 576;

    for (int pix = blockIdx.x; pix < count; pix += gridDim.x) {
        __syncthreads();   // protect xp/dpart reuse across iterations
        const int pid = wl[pix];
        const int b = pid >> 14, yy = (pid >> 7) & 127, xx = pid & 127;
        for (int i = tid; i < 2304; i += 256) {
            int t = i >> 8, ci = i & 255;
            int ky = t / 3, kx = t - ky * 3;
            int gy = yy + ky - 1, gx = xx + kx - 1;
            float v = 0.f;
            if ((unsigned)gy < 128u && (unsigned)gx < 128u)
                v = x[(((size_t)b * 256 + ci) * 128 + gy) * 128 + gx];
            xp[i] = v;
        }
        __syncthreads();

        for (int head = 0; head < 2; head++) {
            const float* gs  = head ? sgs : dgs;
            const float* gb  = head ? sgb : dgb;
            const float* w2  = head ? sw2 : dw2;
            const double* st = head ? dstat2 : dstat1;
            const float* wt  = Wt32 + (size_t)head * 589824;

            double a0 = 0.0, a1 = 0.0, a2 = 0.0, a3 = 0.0;
            for (int jc = 0; jc < 576; jc += 8) {
                float4 wv4[8];
#pragma unroll
                for (int u = 0; u < 8; u++)
                    wv4[u] = *(const float4*)&wt[(size_t)(j0 + jc + u) * 256 + c4];
#pragma unroll
                for (int u = 0; u < 8; u++) {
                    double xv = (double)xp[j0 + jc + u];
                    a0 += xv * (double)wv4[u].x;
                    a1 += xv * (double)wv4[u].y;
                    a2 += xv * (double)wv4[u].z;
                    a3 += xv * (double)wv4[u].w;
                }
            }
            dpart[wv][c4]     = a0;
            dpart[wv][c4 + 1] = a1;
            dpart[wv][c4 + 2] = a2;
            dpart[wv][c4 + 3] = a3;
            __syncthreads();

            {
                const int c = tid;
                double h = dpart[0][c] + dpart[1][c] + dpart[2][c] + dpart[3][c];
                double mu = st[b * 8 + (c >> 5)];
                double rs = st[64 + b * 8 + (c >> 5)];
                double v = (h - mu) * rs * (double)gs[c] + (double)gb[c];
                double g = 0.5 * v * (1.0 + erf(v * 0.70710678118654752440));
                double r0 = g * (double)w2[c];
#pragma unroll
                for (int o = 32; o; o >>= 1) r0 += __shfl_down(r0, o);
                if (lane == 0) wred[head][wv] = r0;
                if (head == 1) {
                    double r1 = g * (double)w2[256 + c];
#pragma unroll
                    for (int o = 32; o; o >>= 1) r1 += __shfl_down(r1, o);
                    if (lane == 0) wred[2][wv] = r1;
                }
            }
            __syncthreads();
        }

        if (tid == 0) {
            double dlv = wred[0][0] + wred[0][1] + wred[0][2] + wred[0][3] + (double)db2[0];
            double c0v = wred[1][0] + wred[1][1] + wred[1][2] + wred[1][3] + (double)sb2[0];
            double c1v = wred[2][0] + wred[2][1] + wred[2][2] + wred[2][3] + (double)sb2[1];
            double s0 = 1.0 / (1.0 + exp(-c0v));
            double s1 = 1.0 / (1.0 + exp(-c1v));
            double t0 = s0, t1 = s0 * s1;
            double e0 = fmax(1.0 - t0, 1e-8);
            double e1 = fmax(t0 - t1, 1e-8);
            double e2 = fmax(t1, 1e-8);
            int am = 0; double bv = e0;
            if (e1 > bv) { bv = e1; am = 1; }
            if (e2 > bv) { bv = e2; am = 2; }
            out[O_LAB + pid] = (dlv >= 0.0) ? (float)(am + 1) : 0.f;
        }
    }
}

// ---------------------------------------------------------------------------
// Exact masked top-k mean per (b,c) via radix select. 32 blocks.
// ---------------------------------------------------------------------------
__global__ __launch_bounds__(256) void topk_kernel(
    const float* __restrict__ outw, const float* __restrict__ mask,
    const float* __restrict__ cntacc, float* __restrict__ topkout)
{
    const int b = blockIdx.x >> 2;
    const int c = blockIdx.x & 3;
    const int tid = threadIdx.x;

    __shared__ int hist[256];
    __shared__ unsigned s_prefix;
    __shared__ int s_want;
    __shared__ float s_red[4];
    __shared__ int s_redi[4];

    float cntf = cntacc[b];
    int cnt = (int)cntf;
    int k = (int)rintf(cntf * 0.2f);
    if (k < 1) k = 1;
    int kmax = cnt > 1 ? cnt : 1;
    if (k > kmax) k = kmax;

    if (tid == 0) { s_prefix = 0u; s_want = k; }

    const float* pv = outw + O_PIX + ((size_t)b * 4 + c) * HW;
    const float* pm = mask + (size_t)b * HW;

    for (int pass = 0; pass < 4; pass++) {
        hist[tid] = 0;
        __syncthreads();
        const int shift = 24 - 8 * pass;
        const unsigned pmask = pass ? (0xFFFFFFFFu << (shift + 8)) : 0u;
        const unsigned prefix = s_prefix;
        for (int p = tid; p < HW; p += 256) {
            float v = (pm[p] > 0.5f) ? pv[p] : -1.0f;
            unsigned bits = __float_as_uint(v);
            unsigned u = (bits & 0x80000000u) ? ~bits : (bits | 0x80000000u);
            if ((u & pmask) == prefix) atomicAdd(&hist[(u >> shift) & 255], 1);
        }
        __syncthreads();
        if (tid == 0) {
            int want = s_want;
            int bin = 255;
            while (bin > 0) {
                int h = hist[bin];
                if (want <= h) break;
                want -= h;
                bin--;
            }
            s_want = want;
            s_prefix = prefix | ((unsigned)bin << shift);
        }
        __syncthreads();
    }
    const unsigned tau = s_prefix;

    float sgt = 0.f; int cgt = 0;
    for (int p = tid; p < HW; p += 256) {
        float v = (pm[p] > 0.5f) ? pv[p] : -1.0f;
        unsigned bits = __float_as_uint(v);
        unsigned u = (bits & 0x80000000u) ? ~bits : (bits | 0x80000000u);
        if (u > tau) { sgt += v; cgt++; }
    }
#pragma unroll
    for (int o = 32; o; o >>= 1) { sgt += __shfl_down(sgt, o); cgt += __shfl_down(cgt, o); }
    if ((tid & 63) == 0) { s_red[tid >> 6] = sgt; s_redi[tid >> 6] = cgt; }
    __syncthreads();
    if (tid == 0) {
        float S = s_red[0] + s_red[1] + s_red[2] + s_red[3];
        int   C = s_redi[0] + s_redi[1] + s_redi[2] + s_redi[3];
        unsigned tb = (tau & 0x80000000u) ? (tau & 0x7FFFFFFFu) : ~tau;
        float tf = __uint_as_float(tb);
        float total = S + (float)(k - C) * tf;
        topkout[b * 4 + c] = total / (float)k;
    }
}

__device__ inline void norm4(float* p)
{
    float a = fmaxf(p[0], 1e-8f), b = fmaxf(p[1], 1e-8f);
    float c = fmaxf(p[2], 1e-8f), d = fmaxf(p[3], 1e-8f);
    float s = fmaxf(a + b + c + d, 1e-8f);
    p[0] = a / s; p[1] = b / s; p[2] = c / s; p[3] = d / s;
}

__global__ void final_kernel(const float* __restrict__ meanacc,
                             const float* __restrict__ cntacc,
                             const float* __restrict__ topkv,
                             float* __restrict__ outw)
{
    int b = threadIdx.x;
    if (b >= 8) return;
    float cnt = cntacc[b];
    bool zero = (cnt == 0.f);
    float denom = fmaxf(cnt, 1.f);
    float m[4], t[4], a[4];
#pragma unroll
    for (int c = 0; c < 4; c++) {
        m[c] = zero ? 0.25f : meanacc[b * 4 + c] / denom;
        t[c] = zero ? 0.25f : topkv[b * 4 + c];
    }
    norm4(m); norm4(t);
#pragma unroll
    for (int c = 0; c < 4; c++) a[c] = 0.7f * m[c] + 0.3f * t[c];
    norm4(a);
    int am = 0; float bv = a[0];
#pragma unroll
    for (int c = 1; c < 4; c++) if (a[c] > bv) { bv = a[c]; am = c; }
#pragma unroll
    for (int c = 0; c < 4; c++) {
        outw[O_MEAN + b * 4 + c] = m[c];
        outw[O_TOPK + b * 4 + c] = t[c];
        outw[O_AGG  + b * 4 + c] = a[c];
    }
    outw[O_ALAB + b] = (float)am;
}

// ---------------------------------------------------------------------------
extern "C" void kernel_launch(void* const* d_in, const int* in_sizes, int n_in,
                              void* d_out, int out_size, void* d_ws, size_t ws_size,
                              hipStream_t stream)
{
    (void)in_sizes; (void)n_in; (void)out_size;
    const float* x    = (const float*)d_in[0];
    const float* mask = (const float*)d_in[1];
    const float* dw1  = (const float*)d_in[2];
    const float* dgs  = (const float*)d_in[3];
    const float* dgb  = (const float*)d_in[4];
    const float* dw2  = (const float*)d_in[5];
    const float* db2  = (const float*)d_in[6];
    const float* sw1  = (const float*)d_in[7];
    const float* sgs  = (const float*)d_in[8];
    const float* sgb  = (const float*)d_in[9];
    const float* sw2  = (const float*)d_in[10];
    const float* sb2  = (const float*)d_in[11];
    float* out = (float*)d_out;

    char* wsb = (char*)d_ws;
    double* dsum1  = (double*)(wsb + BO_DSUM1);
    double* dsum2  = (double*)(wsb + BO_DSUM2);
    float*  fstat1 = (float*)(wsb + BO_FSTAT1);
    float*  fstat2 = (float*)(wsb + BO_FSTAT2);
    double* dstat1 = (double*)(wsb + BO_DSTAT1);
    double* dstat2 = (double*)(wsb + BO_DSTAT2);
    float*  meanacc = (float*)(wsb + BO_MEAN);
    float*  cntacc  = (float*)(wsb + BO_CNT);
    float*  topkv   = (float*)(wsb + BO_TOPK);
    int*    flagc   = (int*)(wsb + BO_FLAGC);
    int*    wl      = (int*)(wsb + BO_WL);

    hipMemsetAsync(d_ws, 0, MEMSET_BYTES, stream);

    dim3 pgrid(64, BB);

    if (ws_size >= MFMA_NEED) {
        ushort* Xh   = (ushort*)(wsb + XP_OFF);
        float*  hb   = (float*)(wsb + HB_OFF);
        ushort* Whh  = (ushort*)(wsb + WH_OFF);
        ushort* Whl  = (ushort*)(wsb + WL_OFF);
        float*  Wt32 = (float*)(wsb + WT32_OFF);

        pack_x_f16<<<8192, 256, 0, stream>>>(x, Xh);

        dim3 cgrid(1024, 2);
        transpose_w<<<2304, 256, 0, stream>>>(dw1, Whh, Whl, Wt32);
        conv3x3_mfma<<<cgrid, 256, 0, stream>>>(Xh, Whh, Whl, hb, dsum1);
        gn_finalize<<<1, 64, 0, stream>>>(dsum1, fstat1, dstat1);
        gn_head<float><<<pgrid, 256, 0, stream>>>(hb, dgs, dgb, dw2, db2,
                                                  fstat1, out + O_DMG, 1);
        transpose_w<<<2304, 256, 0, stream>>>(sw1, Whh, Whl, Wt32 + 589824);
        conv3x3_mfma<<<cgrid, 256, 0, stream>>>(Xh, Whh, Whl, hb, dsum2);
        gn_finalize<<<1, 64, 0, stream>>>(dsum2, fstat2, dstat2);
        gn_head<float><<<pgrid, 256, 0, stream>>>(hb, sgs, sgb, sw2, sb2,
                                                  fstat2, out + O_CORN, 2);

        decode_kernel<<<pgrid, 256, 0, stream>>>(out, mask, meanacc, cntacc, flagc, wl);
        fixup_labels<<<512, 256, 0, stream>>>(x, Wt32, dgs, dgb, dw2, db2,
                                              sgs, sgb, sw2, sb2,
                                              dstat1, dstat2, wl, flagc, out);
        topk_kernel<<<32, 256, 0, stream>>>(out, mask, cntacc, topkv);
        final_kernel<<<1, 64, 0, stream>>>(meanacc, cntacc, topkv, out);
    } else {
        void* hbuf = wsb + XP_OFF;
        dim3 cgrid(HH * BB, CHN / 64);
        const size_t needF32 = XP_OFF + (size_t)BB * CHN * HW * sizeof(float);
        if (ws_size >= needF32) {
            conv3x3_gn_stats<float><<<cgrid, 256, 0, stream>>>(x, dw1, (float*)hbuf, dsum1);
            gn_finalize<<<1, 64, 0, stream>>>(dsum1, fstat1, dstat1);
            gn_head<float><<<pgrid, 256, 0, stream>>>((float*)hbuf, dgs, dgb, dw2, db2,
                                                      fstat1, out + O_DMG, 1);
            conv3x3_gn_stats<float><<<cgrid, 256, 0, stream>>>(x, sw1, (float*)hbuf, dsum2);
            gn_finalize<<<1, 64, 0, stream>>>(dsum2, fstat2, dstat2);
            gn_head<float><<<pgrid, 256, 0, stream>>>((float*)hbuf, sgs, sgb, sw2, sb2,
                                                      fstat2, out + O_CORN, 2);
        } else {
            conv3x3_gn_stats<__hip_bfloat16><<<cgrid, 256, 0, stream>>>(x, dw1, (__hip_bfloat16*)hbuf, dsum1);
            gn_finalize<<<1, 64, 0, stream>>>(dsum1, fstat1, dstat1);
            gn_head<__hip_bfloat16><<<pgrid, 256, 0, stream>>>((__hip_bfloat16*)hbuf, dgs, dgb, dw2, db2,
                                                               fstat1, out + O_DMG, 1);
            conv3x3_gn_stats<__hip_bfloat16><<<cgrid, 256, 0, stream>>>(x, sw1, (__hip_bfloat16*)hbuf, dsum2);
            gn_finalize<<<1, 64, 0, stream>>>(dsum2, fstat2, dstat2);
            gn_head<__hip_bfloat16><<<pgrid, 256, 0, stream>>>((__hip_bfloat16*)hbuf, sgs, sgb, sw2, sb2,
                                                               fstat2, out + O_CORN, 2);
        }
        decode_kernel<<<pgrid, 256, 0, stream>>>(out, mask, meanacc, cntacc, flagc, wl);
        topk_kernel<<<32, 256, 0, stream>>>(out, mask, cntacc, topkv);
        final_kernel<<<1, 64, 0, stream>>>(meanacc, cntacc, topkv, out);
    }
}